// Round 2
// baseline (84.015 us; speedup 1.0000x reference)
//
#include <hip/hip_runtime.h>

// CrossCompress: B=16384, D=128, fp32.
// item_out[b,:]   = v * (e.w_vv) + e * (v.w_ev) + bias_v
// entity_out[b,:] = v * (e.w_ve) + e * (v.w_ee) + bias_e
//
// Layout: 32 lanes per row (float4 each => 128 floats), 2 rows per wave64
// within a pair, and each thread additionally processes row+8192 so the
// 6 weight/bias float4 loads are amortized over 2 rows.
// Shuffle-reduce (xor 16..1) stays within each 32-lane half of the wave.

#define BROWS   16384
#define DDIM    128
#define RSTRIDE 8192   // second row handled by the same thread

__global__ __launch_bounds__(256) void cross_compress_kernel(
    const float* __restrict__ v_in,    // item_embedding   [B,D]
    const float* __restrict__ e_in,    // entity_embedding [B,D]
    const float* __restrict__ w_vv,    // [D]
    const float* __restrict__ w_ve,
    const float* __restrict__ w_ev,
    const float* __restrict__ w_ee,
    const float* __restrict__ bias_v,
    const float* __restrict__ bias_e,
    float* __restrict__ out)           // [2,B,D] flat: item_out then entity_out
{
    const int lane = threadIdx.x & 63;
    const int wave = threadIdx.x >> 6;     // 0..3
    const int half = lane >> 5;            // row within wave-pair
    const int sub  = lane & 31;            // 0..31 -> float4 slot

    const int row0 = blockIdx.x * 8 + wave * 2 + half;   // 0..8191
    const int row1 = row0 + RSTRIDE;
    const int col  = sub * 4;

    // Issue all global loads up front (max MLP).
    const float4 va = *reinterpret_cast<const float4*>(v_in + row0 * DDIM + col);
    const float4 ea = *reinterpret_cast<const float4*>(e_in + row0 * DDIM + col);
    const float4 vb = *reinterpret_cast<const float4*>(v_in + row1 * DDIM + col);
    const float4 eb = *reinterpret_cast<const float4*>(e_in + row1 * DDIM + col);
    const float4 wvv = *reinterpret_cast<const float4*>(w_vv + col);
    const float4 wve = *reinterpret_cast<const float4*>(w_ve + col);
    const float4 wev = *reinterpret_cast<const float4*>(w_ev + col);
    const float4 wee = *reinterpret_cast<const float4*>(w_ee + col);
    const float4 bv  = *reinterpret_cast<const float4*>(bias_v + col);
    const float4 be  = *reinterpret_cast<const float4*>(bias_e + col);

    // Per-lane partial dot products, rows a and b (independent chains).
    float a_vv = ea.x*wvv.x + ea.y*wvv.y + ea.z*wvv.z + ea.w*wvv.w;
    float a_ev = va.x*wev.x + va.y*wev.y + va.z*wev.z + va.w*wev.w;
    float a_ve = ea.x*wve.x + ea.y*wve.y + ea.z*wve.z + ea.w*wve.w;
    float a_ee = va.x*wee.x + va.y*wee.y + va.z*wee.z + va.w*wee.w;

    float b_vv = eb.x*wvv.x + eb.y*wvv.y + eb.z*wvv.z + eb.w*wvv.w;
    float b_ev = vb.x*wev.x + vb.y*wev.y + vb.z*wev.z + vb.w*wev.w;
    float b_ve = eb.x*wve.x + eb.y*wve.y + eb.z*wve.z + eb.w*wve.w;
    float b_ee = vb.x*wee.x + vb.y*wee.y + vb.z*wee.z + vb.w*wee.w;

    // Butterfly reduction within each 32-lane half (offsets <= 16 never
    // cross the half-wave boundary). Two rows' chains interleave.
    #pragma unroll
    for (int off = 16; off >= 1; off >>= 1) {
        a_vv += __shfl_xor(a_vv, off, 64);
        a_ev += __shfl_xor(a_ev, off, 64);
        a_ve += __shfl_xor(a_ve, off, 64);
        a_ee += __shfl_xor(a_ee, off, 64);
        b_vv += __shfl_xor(b_vv, off, 64);
        b_ev += __shfl_xor(b_ev, off, 64);
        b_ve += __shfl_xor(b_ve, off, 64);
        b_ee += __shfl_xor(b_ee, off, 64);
    }

    float4 ioa, eoa, iob, eob;
    ioa.x = va.x * a_vv + ea.x * a_ev + bv.x;
    ioa.y = va.y * a_vv + ea.y * a_ev + bv.y;
    ioa.z = va.z * a_vv + ea.z * a_ev + bv.z;
    ioa.w = va.w * a_vv + ea.w * a_ev + bv.w;

    eoa.x = va.x * a_ve + ea.x * a_ee + be.x;
    eoa.y = va.y * a_ve + ea.y * a_ee + be.y;
    eoa.z = va.z * a_ve + ea.z * a_ee + be.z;
    eoa.w = va.w * a_ve + ea.w * a_ee + be.w;

    iob.x = vb.x * b_vv + eb.x * b_ev + bv.x;
    iob.y = vb.y * b_vv + eb.y * b_ev + bv.y;
    iob.z = vb.z * b_vv + eb.z * b_ev + bv.z;
    iob.w = vb.w * b_vv + eb.w * b_ev + bv.w;

    eob.x = vb.x * b_ve + eb.x * b_ee + be.x;
    eob.y = vb.y * b_ve + eb.y * b_ee + be.y;
    eob.z = vb.z * b_ve + eb.z * b_ee + be.z;
    eob.w = vb.w * b_ve + eb.w * b_ee + be.w;

    float* out_item   = out;
    float* out_entity = out + (size_t)BROWS * DDIM;

    *reinterpret_cast<float4*>(out_item   + (size_t)row0 * DDIM + col) = ioa;
    *reinterpret_cast<float4*>(out_entity + (size_t)row0 * DDIM + col) = eoa;
    *reinterpret_cast<float4*>(out_item   + (size_t)row1 * DDIM + col) = iob;
    *reinterpret_cast<float4*>(out_entity + (size_t)row1 * DDIM + col) = eob;
}

extern "C" void kernel_launch(void* const* d_in, const int* in_sizes, int n_in,
                              void* d_out, int out_size, void* d_ws, size_t ws_size,
                              hipStream_t stream) {
    const float* v_in   = (const float*)d_in[0];
    const float* e_in   = (const float*)d_in[1];
    const float* w_vv   = (const float*)d_in[2];
    const float* w_ve   = (const float*)d_in[3];
    const float* w_ev   = (const float*)d_in[4];
    const float* w_ee   = (const float*)d_in[5];
    const float* bias_v = (const float*)d_in[6];
    const float* bias_e = (const float*)d_in[7];
    float* out = (float*)d_out;

    // 8 row-pairs per 256-thread block; each thread does rows r and r+8192.
    const int grid = RSTRIDE / 8;   // 1024 blocks
    cross_compress_kernel<<<grid, 256, 0, stream>>>(
        v_in, e_in, w_vv, w_ve, w_ev, w_ee, bias_v, bias_e, out);
}